// Round 7
// baseline (438.506 us; speedup 1.0000x reference)
//
#include <hip/hip_runtime.h>
#include <hip/hip_bf16.h>

// Transducer joint: logits[b,t,u,:] = tanh(enc_out[b,t,:] + pred_out[b,u,:]) @ W_out + b_out
// B=4 T=256 U=64 D=512 J=1024 V=1024.
// R4: 256x256/BK=32 gl2lds 2-phase: 184us vocab. R5: tanh-fusion regressed (reverted).
// R6: reg-staged coarse: 193us. R7: 4-phase/8-barrier fine-interleave: ~166us.
// R8: dynamic-128KB path inconclusive (likely attribute failed -> R7 ran). Dropped.
// R9: counted-lgkm schedule @64KB static: per K-step 3 MFMA clusters {8,8,16} and
//     ONE barrier-pair (boundary only). Frag reads issued early, waited with
//     counted lgkmcnt(2/4/0) so the LDS drain hides under MFMA. bf0 kept in regs
//     across the step (no re-read). Staging: B(s+1) at P0/P1 -> buf^1,
//     A(s+2) at the boundary (post-barrier, regions provably read-complete).
//     Boundary vmcnt(2) confirms tile s+1 landed (A(s+2)'s 2 loads stay in
//     flight); vmcnt(0) only at the tail. T1 XCD swizzle + T2 chunk-XOR + T5
//     setprio kept. Fragment/acc/epilogue layout identical to verified R4-R7.

typedef __bf16 bf16x8 __attribute__((ext_vector_type(8)));
typedef float f32x4 __attribute__((ext_vector_type(4)));
typedef unsigned int u32x4 __attribute__((ext_vector_type(4)));
using bf16_t = __hip_bfloat16;

#define B_ 4
#define T_ 256
#define U_ 64
#define DE 512
#define JD 1024
#define VV 1024

// async 16B/lane global->LDS. LDS dest is wave-uniform base + lane*16 (m104/m108).
__device__ __forceinline__ void gl2lds16(const void* g, void* l) {
  __builtin_amdgcn_global_load_lds(
      (__attribute__((address_space(1))) void*)(g),
      (__attribute__((address_space(3))) void*)(l), 16, 0, 0);
}

__device__ __forceinline__ float fast_tanh(float x) {
  float xx = fminf(fmaxf(x, -30.f), 30.f);
  float e = __expf(2.f * xx);
  return 1.f - 2.f * __builtin_amdgcn_rcpf(e + 1.f);
}

// ===================== prep: cvt enc/pred + 3 weight transposes ============
__device__ __forceinline__ void transpose_body(const float* __restrict__ src,
                                               bf16_t* __restrict__ dst,
                                               int K, int N, int bx, int by, int tid,
                                               float (*tile)[33]) {
  const int nt = bx * 32, kt = by * 32;
  const int tx = tid & 31, ty = tid >> 5;  // 32 x 8
#pragma unroll
  for (int i = 0; i < 4; ++i)
    tile[ty + i * 8][tx] = src[(size_t)(kt + ty + i * 8) * N + nt + tx];
  __syncthreads();
#pragma unroll
  for (int i = 0; i < 4; ++i)
    dst[(size_t)(nt + ty + i * 8) * K + kt + tx] = __float2bfloat16(tile[tx][ty + i * 8]);
}

__global__ __launch_bounds__(256) void prep_k(
    const float* __restrict__ enc, const float* __restrict__ pred,
    bf16_t* __restrict__ encb, bf16_t* __restrict__ predb,
    const float* __restrict__ W_enc, bf16_t* __restrict__ WtE,
    const float* __restrict__ W_pred, bf16_t* __restrict__ WtP,
    const float* __restrict__ W_out, bf16_t* __restrict__ WtO) {
  __shared__ float tile[32][33];
  const int bid = blockIdx.x, tid = threadIdx.x;
  if (bid < 640) {
    size_t i = ((size_t)bid * 256 + tid) * 4;
    const float* src;
    bf16_t* dst;
    if (i < (size_t)B_ * T_ * DE) { src = enc; dst = encb; }
    else { i -= (size_t)B_ * T_ * DE; src = pred; dst = predb; }
    f32x4 v = *(const f32x4*)(src + i);
    bf16_t o[4];
#pragma unroll
    for (int z = 0; z < 4; ++z) o[z] = __float2bfloat16(v[z]);
    *(unsigned long long*)(dst + i) = *(unsigned long long*)o;
  } else if (bid < 1152) {
    const int lb = bid - 640;
    transpose_body(W_enc, WtE, DE, JD, lb & 31, lb >> 5, tid, tile);
  } else if (bid < 1664) {
    const int lb = bid - 1152;
    transpose_body(W_pred, WtP, DE, JD, lb & 31, lb >> 5, tid, tile);
  } else {
    const int lb = bid - 1664;
    transpose_body(W_out, WtO, JD, VV, lb & 31, lb >> 5, tid, tile);
  }
}

// ============== proj2: both projections, m97-style 128x128/BK=32 ===========
__device__ __forceinline__ void proj_body(const bf16_t* __restrict__ A,
                                          const bf16_t* __restrict__ Bt,
                                          const float* __restrict__ bias,
                                          float* __restrict__ C,
                                          int m0, int n0, int N, int K) {
  __shared__ bf16_t sA[128 * 32];
  __shared__ bf16_t sB[128 * 32];
  const int tid = threadIdx.x;
  const int wave = tid >> 6, lane = tid & 63;
  const int wm = wave >> 1, wn = wave & 1;

  f32x4 acc[4][4] = {};

  for (int k0 = 0; k0 < K; k0 += 32) {
    __syncthreads();
#pragma unroll
    for (int r = 0; r < 2; ++r) {
      const int base = (wave + 4 * r) * 1024;
      const int row  = (base >> 6) + (lane >> 2);
      const int kel  = (lane & 3) * 8;
      gl2lds16(A  + (size_t)(m0 + row) * K + k0 + kel, (char*)sA + base);
      gl2lds16(Bt + (size_t)(n0 + row) * K + k0 + kel, (char*)sB + base);
    }
    __syncthreads();
    bf16x8 af[4], bfr[4];
    const int kq = (lane >> 4) * 8;
#pragma unroll
    for (int i = 0; i < 4; ++i) {
      af[i]  = *(const bf16x8*)(const void*)(sA + (wm * 64 + i * 16 + (lane & 15)) * 32 + kq);
      bfr[i] = *(const bf16x8*)(const void*)(sB + (wn * 64 + i * 16 + (lane & 15)) * 32 + kq);
    }
#pragma unroll
    for (int i = 0; i < 4; ++i)
#pragma unroll
      for (int j = 0; j < 4; ++j)
        acc[i][j] = __builtin_amdgcn_mfma_f32_16x16x32_bf16(af[i], bfr[j], acc[i][j], 0, 0, 0);
  }

  float bv[4];
#pragma unroll
  for (int j = 0; j < 4; ++j) bv[j] = bias[n0 + wn * 64 + j * 16 + (lane & 15)];
#pragma unroll
  for (int i = 0; i < 4; ++i) {
    const int row = m0 + wm * 64 + i * 16 + ((lane >> 4) << 2);
#pragma unroll
    for (int j = 0; j < 4; ++j) {
      const int col = n0 + wn * 64 + j * 16 + (lane & 15);
#pragma unroll
      for (int rr = 0; rr < 4; ++rr)
        C[(size_t)(row + rr) * N + col] = acc[i][j][rr] + bv[j];
    }
  }
}

__global__ __launch_bounds__(256) void proj2_k(
    const bf16_t* __restrict__ encb, const bf16_t* __restrict__ predb,
    const bf16_t* __restrict__ WtE, const bf16_t* __restrict__ WtP,
    const float* __restrict__ b_enc, const float* __restrict__ b_pred,
    float* __restrict__ enc_o, float* __restrict__ pred_o) {
  int bid = blockIdx.x;
  if (bid < 64) {
    proj_body(encb, WtE, b_enc, enc_o, (bid >> 3) * 128, (bid & 7) * 128, JD, DE);
  } else {
    bid -= 64;
    proj_body(predb, WtP, b_pred, pred_o, (bid >> 3) * 128, (bid & 7) * 128, JD, DE);
  }
}

// ------------- tanh materialize: joint[m][j] = tanh(enc_o + pred_o), bf16 ---
__global__ __launch_bounds__(256) void tanh_mat_k(
    const float* __restrict__ enc_o,   // [B*T][JD]
    const float* __restrict__ pred_o,  // [B*U][JD]
    bf16_t* __restrict__ joint) {      // [B*T*U][JD]
  size_t i = ((size_t)blockIdx.x * 256 + threadIdx.x) * 8;
  const int m = (int)(i >> 10);
  const int j = (int)(i & 1023);
  const int enc_row  = m >> 6;
  const int pred_row = ((m >> 14) << 6) | (m & 63);
  const f32x4* pe = (const f32x4*)(enc_o  + (size_t)enc_row  * JD + j);
  const f32x4* pp = (const f32x4*)(pred_o + (size_t)pred_row * JD + j);
  bf16_t vals[8];
#pragma unroll
  for (int q = 0; q < 2; ++q) {
    f32x4 e = pe[q], p = pp[q];
#pragma unroll
    for (int z = 0; z < 4; ++z)
      vals[q * 4 + z] = __float2bfloat16(fast_tanh(e[z] + p[z]));
  }
  *(u32x4*)(void*)(joint + i) = *(const u32x4*)(const void*)vals;
}

// ====== R9 vocab GEMM: 256x256/BK=32, counted-lgkm 3-cluster schedule ======
// C[M][1024] = A[M][1024] * Bt[1024][1024]^T + bias, M=65536.
// 512 thr = 8 waves (2M x 4N), per-wave 128x64 out, acc 8x4 f32x4.
// LDS 64KB static: dbuf d @ d*32768: A0@0 A1@8K B0@16K B1@24K (each 128r x 64B).
// T2 swizzle: LDS[r][c] = global chunk c ^ ((r>>1)&3) (R4-proven, 0 conflicts).
// Per K-step s (buf D=s&1), invariant at step entry: tile s fully landed &
// barrier'd; A(s+1)'s 2 gl2lds in flight (mine).
//   P0: stage B0(s+1)->D^1 | issue af0,bf0 then bf1 (8 ds_reads) |
//       lgkmcnt(2) -> Q00 (8 MFMA)
//   P1: stage B1(s+1)->D^1 | issue af1 | lgkmcnt(4) -> Q01
//   P2: lgkmcnt(0) -> Q11 + Q10 (16 MFMA; bf0 still in regs)
//   boundary: bar; stage A0,A1(s+2)->D (all reads of D complete: forced by
//       lgkm chain + this barrier); vmcnt(2) [tail: vmcnt(0)] -> tile s+1
//       confirmed landed (FIFO: A(s+1)x2, B0(s+1), B1(s+1) older than A(s+2));
//       bar.
// 2 barriers/step (vs 8 in R7); LDS drain hides under MFMA via counted lgkm.

__global__ __launch_bounds__(512, 2) void vocab_gemm12_k(
    const bf16_t* __restrict__ A,   // [M][JD] joint bf16
    const bf16_t* __restrict__ Bt,  // [VV][JD] W_out^T bf16
    const float* __restrict__ bias, // [VV]
    float* __restrict__ C) {        // [M][VV]
  __shared__ char smem[65536];
  const int tid  = threadIdx.x;
  const int wave = tid >> 6, lane = tid & 63;
  const int wm = wave >> 2, wn = wave & 3;

  // T1: bijective XCD swizzle (grid = 1024, divisible by 8), n-fastest order.
  const int cpx = gridDim.x >> 3;
  const int b   = blockIdx.x;
  const int lb  = (b & 7) * cpx + (b >> 3);
  const int n0  = (lb & 3) * 256;
  const int m0  = (lb >> 2) * 256;

  // staging geometry: LDS slot row = wave*16 + (lane>>2), chunk = lane&3.
  const int sr  = wave * 16 + (lane >> 2);
  const int scg = (lane & 3) ^ ((sr >> 1) & 3);  // inverse-swizzled global chunk
  const int ldst = wave * 1024 + lane * 16;      // linear byte offset in a half
  const bf16_t* gA0 = A  + (size_t)(m0 + sr)       * JD + scg * 8;
  const bf16_t* gA1 = A  + (size_t)(m0 + 128 + sr) * JD + scg * 8;
  const bf16_t* gB0 = Bt + (size_t)(n0 + sr)       * JD + scg * 8;
  const bf16_t* gB1 = Bt + (size_t)(n0 + 128 + sr) * JD + scg * 8;

  const int sl = lane & 15, ql = lane >> 4;

  f32x4 acc[8][4] = {};
  bf16x8 af0v[4], af1v[4], bf0v[2], bf1v[2];
  const int NT = JD / 32;  // 32 K-steps

#define SB() __builtin_amdgcn_sched_barrier(0)

#define STAGE(D, H, S)                                                        \
  do {                                                                        \
    const bf16_t* g_ = ((H) == 0 ? gA0 : (H) == 1 ? gA1 : (H) == 2 ? gB0 : gB1) + (S) * 32; \
    gl2lds16(g_, smem + (D) * 32768 + (H) * 8192 + ldst);                     \
  } while (0)

#define ISSUE_AF(D, QM, DST)                                                  \
  do {                                                                        \
    _Pragma("unroll")                                                         \
    for (int i = 0; i < 4; ++i) {                                             \
      const int lr = (QM) * 64 + i * 16 + sl;                                 \
      (DST)[i] = *(const bf16x8*)(const void*)(                               \
          smem + (D) * 32768 + wm * 8192 + lr * 64 + ((ql ^ ((lr >> 1) & 3)) * 16)); \
    }                                                                         \
  } while (0)

#define ISSUE_BF(D, QN, DST)                                                  \
  do {                                                                        \
    _Pragma("unroll")                                                         \
    for (int jj = 0; jj < 2; ++jj) {                                          \
      const int lr = (wn & 1) * 64 + ((QN) * 2 + jj) * 16 + sl;               \
      (DST)[jj] = *(const bf16x8*)(const void*)(                              \
          smem + (D) * 32768 + 16384 + (wn >> 1) * 8192 + lr * 64 +           \
          ((ql ^ ((lr >> 1) & 3)) * 16));                                     \
    }                                                                         \
  } while (0)

#define MFMA8(AF, BF, QM, QN)                                                 \
  do {                                                                        \
    _Pragma("unroll")                                                         \
    for (int i = 0; i < 4; ++i)                                               \
      _Pragma("unroll")                                                       \
      for (int jj = 0; jj < 2; ++jj)                                          \
        acc[(QM) * 4 + i][(QN) * 2 + jj] = __builtin_amdgcn_mfma_f32_16x16x32_bf16( \
            (AF)[i], (BF)[jj], acc[(QM) * 4 + i][(QN) * 2 + jj], 0, 0, 0);    \
  } while (0)

#define STEP(D, S)                                                            \
  do {                                                                        \
    const int s_ = (S);                                                       \
    /* P0: Q(0,0) */                                                          \
    if (s_ + 1 < NT) STAGE((D) ^ 1, 2, s_ + 1);                               \
    ISSUE_AF(D, 0, af0v); ISSUE_BF(D, 0, bf0v); SB();                         \
    ISSUE_BF(D, 1, bf1v); SB();                                               \
    asm volatile("s_waitcnt lgkmcnt(2)" ::: "memory"); SB();                  \
    __builtin_amdgcn_s_setprio(1); MFMA8(af0v, bf0v, 0, 0);                   \
    __builtin_amdgcn_s_setprio(0); SB();                                      \
    /* P1: Q(0,1) */                                                          \
    if (s_ + 1 < NT) STAGE((D) ^ 1, 3, s_ + 1);                               \
    ISSUE_AF(D, 1, af1v); SB();                                               \
    asm volatile("s_waitcnt lgkmcnt(4)" ::: "memory"); SB();                  \
    __builtin_amdgcn_s_setprio(1); MFMA8(af0v, bf1v, 0, 1);                   \
    __builtin_amdgcn_s_setprio(0); SB();                                      \
    /* P2: Q(1,1) + Q(1,0) (bf0 still live in regs) */                        \
    asm volatile("s_waitcnt lgkmcnt(0)" ::: "memory"); SB();                  \
    __builtin_amdgcn_s_setprio(1); MFMA8(af1v, bf1v, 1, 1);                   \
    MFMA8(af1v, bf0v, 1, 0); __builtin_amdgcn_s_setprio(0); SB();             \
    /* boundary */                                                            \
    if (s_ + 1 < NT) {                                                        \
      __builtin_amdgcn_s_barrier(); SB();                                     \
      if (s_ + 2 < NT) {                                                      \
        STAGE(D, 0, s_ + 2); STAGE(D, 1, s_ + 2);                             \
        asm volatile("s_waitcnt vmcnt(2)" ::: "memory");                      \
      } else {                                                                \
        asm volatile("s_waitcnt vmcnt(0)" ::: "memory");                      \
      }                                                                       \
      __builtin_amdgcn_s_barrier(); SB();                                     \
    }                                                                         \
  } while (0)

  // prologue: tile 0 all halves -> buf0; A(1) -> buf1; confirm tile 0.
  STAGE(0, 0, 0); STAGE(0, 1, 0); STAGE(0, 2, 0); STAGE(0, 3, 0);
  STAGE(1, 0, 1); STAGE(1, 1, 1);
  asm volatile("s_waitcnt vmcnt(2)" ::: "memory");  // tile0 landed; A(1) flying
  __builtin_amdgcn_s_barrier();
  SB();

  for (int it = 0; it < NT / 2; ++it) {
    STEP(0, 2 * it);
    STEP(1, 2 * it + 1);
  }

#undef STEP
#undef MFMA8
#undef ISSUE_BF
#undef ISSUE_AF
#undef STAGE
#undef SB

  // ---- epilogue (bias here so the K-loop has no stray VMEM) ----
  float bv[4];
#pragma unroll
  for (int j = 0; j < 4; ++j) bv[j] = bias[n0 + wn * 64 + j * 16 + (lane & 15)];
#pragma unroll
  for (int i = 0; i < 8; ++i) {
    const int row = m0 + wm * 128 + i * 16 + ((lane >> 4) << 2);
#pragma unroll
    for (int j = 0; j < 4; ++j) {
      const int col = n0 + wn * 64 + j * 16 + (lane & 15);
#pragma unroll
      for (int rr = 0; rr < 4; ++rr)
        C[(size_t)(row + rr) * VV + col] = acc[i][j][rr] + bv[j];
    }
  }
}

extern "C" void kernel_launch(void* const* d_in, const int* in_sizes, int n_in,
                              void* d_out, int out_size, void* d_ws, size_t ws_size,
                              hipStream_t stream) {
  const float* enc    = (const float*)d_in[0];  // [4,256,512]
  const float* pred   = (const float*)d_in[1];  // [4,64,512]
  const float* W_enc  = (const float*)d_in[2];  // [512,1024]
  const float* b_enc  = (const float*)d_in[3];  // [1024]
  const float* W_pred = (const float*)d_in[4];  // [512,1024]
  const float* b_pred = (const float*)d_in[5];  // [1024]
  const float* W_out  = (const float*)d_in[6];  // [1024,1024]
  const float* b_out  = (const float*)d_in[7];  // [1024]
  float* out = (float*)d_out;                   // [4,256,64,1024]

  char* ws = (char*)d_ws;
  bf16_t* encb   = (bf16_t*)(ws + 0x000000);  // 1 MB   [1024][512]
  bf16_t* predb  = (bf16_t*)(ws + 0x100000);  // 256 KB [256][512]
  bf16_t* WtE    = (bf16_t*)(ws + 0x140000);  // 1 MB   [1024][512]
  bf16_t* WtP    = (bf16_t*)(ws + 0x240000);  // 1 MB   [1024][512]
  bf16_t* WtO    = (bf16_t*)(ws + 0x340000);  // 2 MB   [1024][1024]
  float*  enc_o  = (float*) (ws + 0x540000);  // 4 MB   [1024][1024]
  float*  pred_o = (float*) (ws + 0x940000);  // 1 MB   [256][1024]
  bf16_t* joint  = (bf16_t*)(ws + 0xA40000);  // 128 MB [65536][1024]

  // 1) prep: cvt enc/pred + transpose all three weights
  prep_k<<<2688, 256, 0, stream>>>(enc, pred, encb, predb, W_enc, WtE, W_pred, WtP, W_out, WtO);
  // 2) both projections (bias folded)
  proj2_k<<<80, 256, 0, stream>>>(encb, predb, WtE, WtP, b_enc, b_pred, enc_o, pred_o);
  // 3) tanh materialize (bf16 joint)
  tanh_mat_k<<<(B_*T_*U_) * JD / (8 * 256), 256, 0, stream>>>(enc_o, pred_o, joint);
  // 4) counted-lgkm vocab GEMM
  vocab_gemm12_k<<<dim3(((B_*T_*U_) / 256) * (VV / 256)), 512, 0, stream>>>(
      joint, WtO, b_out, out);
}